// Round 9
// baseline (159.893 us; speedup 1.0000x reference)
//
#include <hip/hip_runtime.h>
#include <cstddef>

#define NB 4
#define NC 256
#define ND 128
#define NH 128
#define NW 128
#define NHW (NH*NW)
#define NT 16384
#define NBKT 1024   // 4 batches x 16x16 tiles of 8x8 px
#define CAP 192     // per-bucket capacity (mean 64, overflow probability ~e^-64)

typedef short   short8  __attribute__((ext_vector_type(8)));
typedef float   floatx4 __attribute__((ext_vector_type(4)));
typedef float   floatx2 __attribute__((ext_vector_type(2)));

__device__ __forceinline__ unsigned pk_bf16(float a, float b) {
    unsigned ua = __float_as_uint(a);
    unsigned ub = __float_as_uint(b);
    ua += 0x7fffu + ((ua >> 16) & 1u);
    ub += 0x7fffu + ((ub >> 16) & 1u);
    return (ua >> 16) | (ub & 0xffff0000u);
}

// ---- fp8 e4m3 (OCP) HW cvt ----
__device__ __forceinline__ unsigned fp8x4_from_f32(float v0, float v1, float v2, float v3) {
    int r = 0;
    r = __builtin_amdgcn_cvt_pk_fp8_f32(v0, v1, r, false);
    r = __builtin_amdgcn_cvt_pk_fp8_f32(v2, v3, r, true);
    return (unsigned)r;
}
template <bool HI>
__device__ __forceinline__ floatx2 fp8x2_to_f32(unsigned w) {
    return __builtin_amdgcn_cvt_pk_f32_fp8((int)w, HI);
}

__device__ __forceinline__ int bucket_of(float cx, float cy, int b) {
    int x0 = (int)floorf(cx * (float)(NW - 1));
    int y0 = (int)floorf(cy * (float)(NH - 1));
    x0 = min(max(x0, 0), NW - 1);
    y0 = min(max(y0, 0), NH - 1);
    return b * 256 + (y0 >> 3) * 16 + (x0 >> 3);
}

// prep: blocks [0,16) compute Wf = W1 @ Wp (fp32 VALU, rounded once to bf16);
// block 16 zeros the bucket counters (replaces the hipMemsetAsync launch).
// Wf[e][c] = sum_d W1[e][d] * Wp[d][c]; block bi covers e in [bi*8, bi*8+8).
__global__ __launch_bounds__(256)
void prep_kernel(const float* __restrict__ W1, const float* __restrict__ Wp,
                 unsigned short* __restrict__ Wfbf, int* __restrict__ counts)
{
    const int bi = blockIdx.x;
    const int t  = threadIdx.x;
    if (bi == 16) {
        counts[t*4+0] = 0; counts[t*4+1] = 0; counts[t*4+2] = 0; counts[t*4+3] = 0;
        return;
    }
    const int e  = bi*8 + (t >> 5);
    const int c0 = (t & 31) * 8;
    float acc[8];
    #pragma unroll
    for (int j = 0; j < 8; ++j) acc[j] = 0.f;
    const float* w1r = W1 + (size_t)e*ND;
    const float* wpc = Wp + c0;
    for (int d = 0; d < ND; ++d) {
        const float s = w1r[d];
        float4 p0 = *(const float4*)(wpc + (size_t)d*NC);
        float4 p1 = *(const float4*)(wpc + (size_t)d*NC + 4);
        acc[0] = fmaf(s, p0.x, acc[0]); acc[1] = fmaf(s, p0.y, acc[1]);
        acc[2] = fmaf(s, p0.z, acc[2]); acc[3] = fmaf(s, p0.w, acc[3]);
        acc[4] = fmaf(s, p1.x, acc[4]); acc[5] = fmaf(s, p1.y, acc[5]);
        acc[6] = fmaf(s, p1.z, acc[6]); acc[7] = fmaf(s, p1.w, acc[7]);
    }
    uint4 pk = make_uint4(pk_bf16(acc[0],acc[1]), pk_bf16(acc[2],acc[3]),
                          pk_bf16(acc[4],acc[5]), pk_bf16(acc[6],acc[7]));
    *(uint4*)&Wfbf[(size_t)e*NC + c0] = pk;
}

// Fused: blocks [0,128) bucket-scatter; [128,1152) projection GEMM
// vmf[b][p][e] = sum_c Wf[e][c]*fmap[b][c][p], fp8 e4m3 channel-last.
// d-HALF per block (32 KB LDS), Wf bf16 staged once to LDS as A-fragments,
// K-loop with explicit double-buffered B prefetch (16 loads in flight).
__global__ __launch_bounds__(512, 4)
void proj_fill_kernel(const float* __restrict__ fmap,
                      const unsigned short* __restrict__ Wfbf,
                      const float* __restrict__ coords,
                      unsigned char* __restrict__ vmf,
                      int* __restrict__ counts, int* __restrict__ order)
{
    const int bi0 = blockIdx.x;
    if (bi0 < 128) {         // ---- bucket scatter ----
        const int g = bi0 * 512 + threadIdx.x;
        const float cx = coords[(size_t)g*2 + 0];
        const float cy = coords[(size_t)g*2 + 1];
        const int bkt = bucket_of(cx, cy, g >> 14);
        const int pos = atomicAdd(&counts[bkt], 1);
        if (pos < CAP) order[bkt*CAP + pos] = g;
        return;
    }
    const int bi = bi0 - 128;            // [0, 1024)
    __shared__ unsigned short awp[4*8*64*8];   // [dt][ch][lane][8 bf16] = 32 KB

    const int t    = threadIdx.x;
    const int lane = t & 63;
    const int w    = t >> 6;
    const int l15  = lane & 15;
    const int q    = lane >> 4;
    const int cq   = q * 8;

    const int h    = bi & 1;                        // d-half
    const int bi2  = bi >> 1;                       // [0, 512)
    const int b    = (bi2 & 7) >> 1;                // XCD-aware: 2 XCDs per batch
    const int slot = ((bi2 >> 3) << 1) | (bi2 & 1); // [0,128)
    const int p    = slot*128 + w*16 + l15;

    // ---- stage this half's Wf rows -> LDS A-fragments ----
    {
        const int dt  = w >> 1;
        const int ch0 = (w & 1) * 4;
        #pragma unroll
        for (int cc = 0; cc < 4; ++cc) {
            const int ch = ch0 + cc;
            uint4 v = *(const uint4*)&Wfbf[(size_t)(h*64 + dt*16 + l15)*NC + ch*32 + cq];
            *(uint4*)&awp[((dt*8 + ch)*64 + lane)*8] = v;
        }
    }
    __syncthreads();

    floatx4 acc[4];
    #pragma unroll
    for (int i = 0; i < 4; ++i) acc[i] = (floatx4)(0.f);

    const float* fbase = fmap + (size_t)b*NC*NHW + p;

    float f[2][8];
    #pragma unroll
    for (int j = 0; j < 8; ++j) f[0][j] = fbase[(size_t)(cq + j)*NHW];

    #pragma unroll
    for (int c0 = 0; c0 < 8; ++c0) {
        const int cur = c0 & 1;
        if (c0 < 7) {                    // prefetch next chunk while we compute
            const float* bp = fbase + (size_t)((c0+1)*32 + cq)*NHW;
            #pragma unroll
            for (int j = 0; j < 8; ++j) f[cur^1][j] = bp[(size_t)j*NHW];
        }
        union { short8 v; unsigned u[4]; } bc;
        #pragma unroll
        for (int j = 0; j < 4; ++j) bc.u[j] = pk_bf16(f[cur][2*j], f[cur][2*j+1]);
        #pragma unroll
        for (int dt = 0; dt < 4; ++dt) {
            short8 afr = *(const short8*)&awp[((dt*8 + c0)*64 + lane)*8];
            acc[dt] = __builtin_amdgcn_mfma_f32_16x16x32_bf16(afr, bc.v, acc[dt], 0, 0, 0);
        }
    }
    // ---- epilogue: C row=(q*4+reg)->e, col=l15->p; 4 fp8 per dword ----
    unsigned char* vrow = vmf + ((size_t)(b*NHW + p))*ND + h*64;
    #pragma unroll
    for (int dt = 0; dt < 4; ++dt) {
        floatx4 v = acc[dt];
        *(unsigned*)&vrow[dt*16 + q*4] = fp8x4_from_f32(v[0], v[1], v[2], v[3]);
    }
}

// Gather over spatially-bucketed points. vmf already holds W1-folded features,
// so per point: h = relu(stencil_mean + b1); out = coords + tanh(W2 h + b2)*MD.
// 8 lanes per point (16 fp8 ch each), shfl_xor reduce over the 8 lanes,
// NO LDS, NO barriers -> occupancy is VGPR-bound only.
__global__ __launch_bounds__(512, 4)
void gather_kernel(const unsigned char* __restrict__ vmf, const float* __restrict__ coords,
                   const int* __restrict__ counts, const int* __restrict__ order,
                   const float* __restrict__ b1, const float* __restrict__ W2,
                   const float* __restrict__ b2, float* __restrict__ out)
{
    const int t   = threadIdx.x;
    const int bkt = blockIdx.x;
    const int n   = min(counts[bkt], CAP);
    const int grp = t >> 3;
    const int c8  = t & 7;
    const int e0  = c8 * 16;
    const float b20 = b2[0], b21 = b2[1];
    const float MD = 0.5f / 512.0f;
    const float s9 = 1.f / 9.f;

    for (int i = grp; i < n; i += 64) {
        const int g = order[bkt*CAP + i];
        const int b = g >> 14;
        const float cx = coords[(size_t)g*2 + 0];
        const float cy = coords[(size_t)g*2 + 1];
        const float ix = cx * (float)(NW - 1);
        const float iy = cy * (float)(NH - 1);
        const float x0f = floorf(ix), y0f = floorf(iy);
        const int x0 = (int)x0f, y0 = (int)y0f;
        const float wx1 = ix - x0f, wy1 = iy - y0f;
        const float wxv[4] = {1.f - wx1, 1.f, 1.f, wx1};
        const float wyv[4] = {1.f - wy1, 1.f, 1.f, wy1};
        floatx2 acc[8];
        #pragma unroll
        for (int k = 0; k < 8; ++k) acc[k] = (floatx2)(0.f);
        const unsigned char* vmb = vmf + (size_t)b*NHW*ND + e0;
        #pragma unroll
        for (int j = 0; j < 4; ++j) {
            const int Y  = y0 - 1 + j;
            const int Yc = min(max(Y, 0), NH-1);
            const bool vy = (Y >= 0) & (Y < NH);
            #pragma unroll
            for (int ii = 0; ii < 4; ++ii) {
                const int X  = x0 - 1 + ii;
                const int Xc = min(max(X, 0), NW-1);
                const bool vx = (X >= 0) & (X < NW);
                const float wgt = (vx & vy) ? wxv[ii]*wyv[j] : 0.f;  // zeros pad
                uint4 u = *(const uint4*)(vmb + (size_t)(Yc*NW + Xc)*ND);
                const floatx2 w2v = {wgt, wgt};
                acc[0] += w2v * fp8x2_to_f32<false>(u.x);
                acc[1] += w2v * fp8x2_to_f32<true >(u.x);
                acc[2] += w2v * fp8x2_to_f32<false>(u.y);
                acc[3] += w2v * fp8x2_to_f32<true >(u.y);
                acc[4] += w2v * fp8x2_to_f32<false>(u.z);
                acc[5] += w2v * fp8x2_to_f32<true >(u.z);
                acc[6] += w2v * fp8x2_to_f32<false>(u.w);
                acc[7] += w2v * fp8x2_to_f32<true >(u.w);
            }
        }
        // epilogue: bias + relu + W2 dot over this lane's 16 channels
        float s0 = 0.f, s1 = 0.f;
        #pragma unroll
        for (int k = 0; k < 8; ++k) {
            float2 bb = *(const float2*)&b1[e0 + 2*k];
            float h0 = fmaxf(fmaf(acc[k].x, s9, bb.x), 0.f);
            float h1 = fmaxf(fmaf(acc[k].y, s9, bb.y), 0.f);
            float2 wa = *(const float2*)&W2[e0 + 2*k];
            float2 wb = *(const float2*)&W2[ND + e0 + 2*k];
            s0 = fmaf(h0, wa.x, fmaf(h1, wa.y, s0));
            s1 = fmaf(h0, wb.x, fmaf(h1, wb.y, s1));
        }
        s0 += __shfl_xor(s0, 1); s0 += __shfl_xor(s0, 2); s0 += __shfl_xor(s0, 4);
        s1 += __shfl_xor(s1, 1); s1 += __shfl_xor(s1, 2); s1 += __shfl_xor(s1, 4);
        if (c8 == 0) {
            float2 o = make_float2(cx + tanhf(s0 + b20) * MD,
                                   cy + tanhf(s1 + b21) * MD);
            *(float2*)&out[(size_t)g*2] = o;
        }
    }
}

extern "C" void kernel_launch(void* const* d_in, const int* in_sizes, int n_in,
                              void* d_out, int out_size, void* d_ws, size_t ws_size,
                              hipStream_t stream)
{
    const float* fmap   = (const float*)d_in[0];
    const float* coords = (const float*)d_in[1];
    const float* Wp     = (const float*)d_in[2];
    const float* W1     = (const float*)d_in[3];
    const float* b1     = (const float*)d_in[4];
    const float* W2     = (const float*)d_in[5];
    const float* b2     = (const float*)d_in[6];
    float* out = (float*)d_out;

    // ws layout
    unsigned char* vmf = (unsigned char*)d_ws;                        // 8 MB fp8
    char* base = (char*)d_ws + (size_t)NB*NHW*ND;
    unsigned short* Wfbf = (unsigned short*)base;                     // 64 KB bf16
    int* counts = (int*)(base + 65536);                               // 4 KB
    int* order  = (int*)(base + 65536 + 4096);                        // 768 KB

    prep_kernel     <<<dim3(17),         256, 0, stream>>>(W1, Wp, Wfbf, counts);
    proj_fill_kernel<<<dim3(128 + 1024), 512, 0, stream>>>(fmap, Wfbf, coords,
                                                           vmf, counts, order);
    gather_kernel   <<<dim3(NBKT),       512, 0, stream>>>(vmf, coords, counts, order,
                                                           b1, W2, b2, out);
}

// Round 10
// 159.627 us; speedup vs baseline: 1.0017x; 1.0017x over previous
//
#include <hip/hip_runtime.h>
#include <cstddef>

#define NB 4
#define NC 256
#define ND 128
#define NH 128
#define NW 128
#define NHW (NH*NW)
#define NT 16384
#define NBKT 1024   // 4 batches x 16x16 tiles of 8x8 px
#define CAP 192     // per-bucket capacity (mean 64, overflow probability ~e^-64)

typedef short   short8  __attribute__((ext_vector_type(8)));
typedef float   floatx4 __attribute__((ext_vector_type(4)));
typedef float   floatx2 __attribute__((ext_vector_type(2)));

__device__ __forceinline__ unsigned pk_bf16(float a, float b) {
    unsigned ua = __float_as_uint(a);
    unsigned ub = __float_as_uint(b);
    ua += 0x7fffu + ((ua >> 16) & 1u);
    ub += 0x7fffu + ((ub >> 16) & 1u);
    return (ua >> 16) | (ub & 0xffff0000u);
}

// ---- fp8 e4m3 (OCP) HW cvt ----
__device__ __forceinline__ unsigned fp8x4_from_f32(float v0, float v1, float v2, float v3) {
    int r = 0;
    r = __builtin_amdgcn_cvt_pk_fp8_f32(v0, v1, r, false);
    r = __builtin_amdgcn_cvt_pk_fp8_f32(v2, v3, r, true);
    return (unsigned)r;
}
template <bool HI>
__device__ __forceinline__ floatx2 fp8x2_to_f32(unsigned w) {
    return __builtin_amdgcn_cvt_pk_f32_fp8((int)w, HI);
}

__device__ __forceinline__ int bucket_of(float cx, float cy, int b) {
    int x0 = (int)floorf(cx * (float)(NW - 1));
    int y0 = (int)floorf(cy * (float)(NH - 1));
    x0 = min(max(x0, 0), NW - 1);
    y0 = min(max(y0, 0), NH - 1);
    return b * 256 + (y0 >> 3) * 16 + (x0 >> 3);
}

// prep: blocks [0,16) compute Wf = W1 @ Wp (fp32 VALU, rounded once to bf16);
// block 16 zeros the bucket counters.
__global__ __launch_bounds__(256)
void prep_kernel(const float* __restrict__ W1, const float* __restrict__ Wp,
                 unsigned short* __restrict__ Wfbf, int* __restrict__ counts)
{
    const int bi = blockIdx.x;
    const int t  = threadIdx.x;
    if (bi == 16) {
        counts[t*4+0] = 0; counts[t*4+1] = 0; counts[t*4+2] = 0; counts[t*4+3] = 0;
        return;
    }
    const int e  = bi*8 + (t >> 5);
    const int c0 = (t & 31) * 8;
    float acc[8];
    #pragma unroll
    for (int j = 0; j < 8; ++j) acc[j] = 0.f;
    const float* w1r = W1 + (size_t)e*ND;
    const float* wpc = Wp + c0;
    for (int d = 0; d < ND; ++d) {
        const float s = w1r[d];
        float4 p0 = *(const float4*)(wpc + (size_t)d*NC);
        float4 p1 = *(const float4*)(wpc + (size_t)d*NC + 4);
        acc[0] = fmaf(s, p0.x, acc[0]); acc[1] = fmaf(s, p0.y, acc[1]);
        acc[2] = fmaf(s, p0.z, acc[2]); acc[3] = fmaf(s, p0.w, acc[3]);
        acc[4] = fmaf(s, p1.x, acc[4]); acc[5] = fmaf(s, p1.y, acc[5]);
        acc[6] = fmaf(s, p1.z, acc[6]); acc[7] = fmaf(s, p1.w, acc[7]);
    }
    uint4 pk = make_uint4(pk_bf16(acc[0],acc[1]), pk_bf16(acc[2],acc[3]),
                          pk_bf16(acc[4],acc[5]), pk_bf16(acc[6],acc[7]));
    *(uint4*)&Wfbf[(size_t)e*NC + c0] = pk;
}

// Fused: blocks [0,128) bucket-scatter; [128,1152) projection GEMM
// vmf[b][p][e] = sum_c Wf[e][c]*fmap[b][c][p], fp8 e4m3 channel-last.
// d-HALF per block (32 KB LDS). ALL 64 B-loads hoisted upfront into VGPRs:
// one latency drain per wave instead of 8 chained chunk-waits (round 9 was
// latency-bound at VALUBusy 11% / MfmaUtil 3.4% with only ~8-16 loads in
// flight per chunk boundary).
__global__ __launch_bounds__(512, 4)
void proj_fill_kernel(const float* __restrict__ fmap,
                      const unsigned short* __restrict__ Wfbf,
                      const float* __restrict__ coords,
                      unsigned char* __restrict__ vmf,
                      int* __restrict__ counts, int* __restrict__ order)
{
    const int bi0 = blockIdx.x;
    if (bi0 < 128) {         // ---- bucket scatter ----
        const int g = bi0 * 512 + threadIdx.x;
        const float cx = coords[(size_t)g*2 + 0];
        const float cy = coords[(size_t)g*2 + 1];
        const int bkt = bucket_of(cx, cy, g >> 14);
        const int pos = atomicAdd(&counts[bkt], 1);
        if (pos < CAP) order[bkt*CAP + pos] = g;
        return;
    }
    const int bi = bi0 - 128;            // [0, 1024)
    __shared__ unsigned short awp[4*8*64*8];   // [dt][ch][lane][8 bf16] = 32 KB

    const int t    = threadIdx.x;
    const int lane = t & 63;
    const int w    = t >> 6;
    const int l15  = lane & 15;
    const int q    = lane >> 4;
    const int cq   = q * 8;

    const int h    = bi & 1;                        // d-half
    const int bi2  = bi >> 1;                       // [0, 512)
    const int b    = (bi2 & 7) >> 1;                // XCD-aware: 2 XCDs per batch
    const int slot = ((bi2 >> 3) << 1) | (bi2 & 1); // [0,128)
    const int p    = slot*128 + w*16 + l15;

    // ---- stage this half's Wf rows -> LDS A-fragments ----
    {
        const int dt  = w >> 1;
        const int ch0 = (w & 1) * 4;
        #pragma unroll
        for (int cc = 0; cc < 4; ++cc) {
            const int ch = ch0 + cc;
            uint4 v = *(const uint4*)&Wfbf[(size_t)(h*64 + dt*16 + l15)*NC + ch*32 + cq];
            *(uint4*)&awp[((dt*8 + ch)*64 + lane)*8] = v;
        }
    }
    __syncthreads();

    floatx4 acc[4];
    #pragma unroll
    for (int i = 0; i < 4; ++i) acc[i] = (floatx4)(0.f);

    const float* fbase = fmap + (size_t)b*NC*NHW + p;

    // ---- ALL 64 B-loads issued upfront: one drain, max memory parallelism ----
    float f[64];
    #pragma unroll
    for (int c0 = 0; c0 < 8; ++c0)
        #pragma unroll
        for (int j = 0; j < 8; ++j)
            f[c0*8 + j] = fbase[(size_t)(c0*32 + cq + j)*NHW];

    #pragma unroll
    for (int c0 = 0; c0 < 8; ++c0) {
        union { short8 v; unsigned u[4]; } bc;
        #pragma unroll
        for (int j = 0; j < 4; ++j) bc.u[j] = pk_bf16(f[c0*8 + 2*j], f[c0*8 + 2*j+1]);
        #pragma unroll
        for (int dt = 0; dt < 4; ++dt) {
            short8 afr = *(const short8*)&awp[((dt*8 + c0)*64 + lane)*8];
            acc[dt] = __builtin_amdgcn_mfma_f32_16x16x32_bf16(afr, bc.v, acc[dt], 0, 0, 0);
        }
    }
    // ---- epilogue: C row=(q*4+reg)->e, col=l15->p; 4 fp8 per dword ----
    unsigned char* vrow = vmf + ((size_t)(b*NHW + p))*ND + h*64;
    #pragma unroll
    for (int dt = 0; dt < 4; ++dt) {
        floatx4 v = acc[dt];
        *(unsigned*)&vrow[dt*16 + q*4] = fp8x4_from_f32(v[0], v[1], v[2], v[3]);
    }
}

// Gather over spatially-bucketed points. vmf holds W1-folded features:
// h = relu(stencil_mean + b1); out = coords + tanh(W2 h + b2)*MD.
// 8 lanes per point (16 fp8 ch each), shfl_xor reduce, NO LDS, NO barriers.
__global__ __launch_bounds__(512, 4)
void gather_kernel(const unsigned char* __restrict__ vmf, const float* __restrict__ coords,
                   const int* __restrict__ counts, const int* __restrict__ order,
                   const float* __restrict__ b1, const float* __restrict__ W2,
                   const float* __restrict__ b2, float* __restrict__ out)
{
    const int t   = threadIdx.x;
    const int bkt = blockIdx.x;
    const int n   = min(counts[bkt], CAP);
    const int grp = t >> 3;
    const int c8  = t & 7;
    const int e0  = c8 * 16;
    const float b20 = b2[0], b21 = b2[1];
    const float MD = 0.5f / 512.0f;
    const float s9 = 1.f / 9.f;

    for (int i = grp; i < n; i += 64) {
        const int g = order[bkt*CAP + i];
        const int b = g >> 14;
        const float cx = coords[(size_t)g*2 + 0];
        const float cy = coords[(size_t)g*2 + 1];
        const float ix = cx * (float)(NW - 1);
        const float iy = cy * (float)(NH - 1);
        const float x0f = floorf(ix), y0f = floorf(iy);
        const int x0 = (int)x0f, y0 = (int)y0f;
        const float wx1 = ix - x0f, wy1 = iy - y0f;
        const float wxv[4] = {1.f - wx1, 1.f, 1.f, wx1};
        const float wyv[4] = {1.f - wy1, 1.f, 1.f, wy1};
        floatx2 acc[8];
        #pragma unroll
        for (int k = 0; k < 8; ++k) acc[k] = (floatx2)(0.f);
        const unsigned char* vmb = vmf + (size_t)b*NHW*ND + e0;
        #pragma unroll
        for (int j = 0; j < 4; ++j) {
            const int Y  = y0 - 1 + j;
            const int Yc = min(max(Y, 0), NH-1);
            const bool vy = (Y >= 0) & (Y < NH);
            #pragma unroll
            for (int ii = 0; ii < 4; ++ii) {
                const int X  = x0 - 1 + ii;
                const int Xc = min(max(X, 0), NW-1);
                const bool vx = (X >= 0) & (X < NW);
                const float wgt = (vx & vy) ? wxv[ii]*wyv[j] : 0.f;  // zeros pad
                uint4 u = *(const uint4*)(vmb + (size_t)(Yc*NW + Xc)*ND);
                const floatx2 w2v = {wgt, wgt};
                acc[0] += w2v * fp8x2_to_f32<false>(u.x);
                acc[1] += w2v * fp8x2_to_f32<true >(u.x);
                acc[2] += w2v * fp8x2_to_f32<false>(u.y);
                acc[3] += w2v * fp8x2_to_f32<true >(u.y);
                acc[4] += w2v * fp8x2_to_f32<false>(u.z);
                acc[5] += w2v * fp8x2_to_f32<true >(u.z);
                acc[6] += w2v * fp8x2_to_f32<false>(u.w);
                acc[7] += w2v * fp8x2_to_f32<true >(u.w);
            }
        }
        // epilogue: bias + relu + W2 dot over this lane's 16 channels
        float s0 = 0.f, s1 = 0.f;
        #pragma unroll
        for (int k = 0; k < 8; ++k) {
            float2 bb = *(const float2*)&b1[e0 + 2*k];
            float h0 = fmaxf(fmaf(acc[k].x, s9, bb.x), 0.f);
            float h1 = fmaxf(fmaf(acc[k].y, s9, bb.y), 0.f);
            float2 wa = *(const float2*)&W2[e0 + 2*k];
            float2 wb = *(const float2*)&W2[ND + e0 + 2*k];
            s0 = fmaf(h0, wa.x, fmaf(h1, wa.y, s0));
            s1 = fmaf(h0, wb.x, fmaf(h1, wb.y, s1));
        }
        s0 += __shfl_xor(s0, 1); s0 += __shfl_xor(s0, 2); s0 += __shfl_xor(s0, 4);
        s1 += __shfl_xor(s1, 1); s1 += __shfl_xor(s1, 2); s1 += __shfl_xor(s1, 4);
        if (c8 == 0) {
            float2 o = make_float2(cx + tanhf(s0 + b20) * MD,
                                   cy + tanhf(s1 + b21) * MD);
            *(float2*)&out[(size_t)g*2] = o;
        }
    }
}

extern "C" void kernel_launch(void* const* d_in, const int* in_sizes, int n_in,
                              void* d_out, int out_size, void* d_ws, size_t ws_size,
                              hipStream_t stream)
{
    const float* fmap   = (const float*)d_in[0];
    const float* coords = (const float*)d_in[1];
    const float* Wp     = (const float*)d_in[2];
    const float* W1     = (const float*)d_in[3];
    const float* b1     = (const float*)d_in[4];
    const float* W2     = (const float*)d_in[5];
    const float* b2     = (const float*)d_in[6];
    float* out = (float*)d_out;

    // ws layout
    unsigned char* vmf = (unsigned char*)d_ws;                        // 8 MB fp8
    char* base = (char*)d_ws + (size_t)NB*NHW*ND;
    unsigned short* Wfbf = (unsigned short*)base;                     // 64 KB bf16
    int* counts = (int*)(base + 65536);                               // 4 KB
    int* order  = (int*)(base + 65536 + 4096);                        // 768 KB

    prep_kernel     <<<dim3(17),         256, 0, stream>>>(W1, Wp, Wfbf, counts);
    proj_fill_kernel<<<dim3(128 + 1024), 512, 0, stream>>>(fmap, Wfbf, coords,
                                                           vmf, counts, order);
    gather_kernel   <<<dim3(NBKT),       512, 0, stream>>>(vmf, coords, counts, order,
                                                           b1, W2, b2, out);
}

// Round 11
// 157.423 us; speedup vs baseline: 1.0157x; 1.0140x over previous
//
#include <hip/hip_runtime.h>
#include <cstddef>

#define NB 4
#define NC 256
#define ND 128
#define NH 128
#define NW 128
#define NHW (NH*NW)
#define NT 16384
#define NBKT 1024   // 4 batches x 16x16 tiles of 8x8 px
#define CAP 192     // per-bucket capacity (mean 64, overflow probability ~e^-64)

typedef short   short8  __attribute__((ext_vector_type(8)));
typedef float   floatx4 __attribute__((ext_vector_type(4)));
typedef float   floatx2 __attribute__((ext_vector_type(2)));

__device__ __forceinline__ unsigned pk_bf16(float a, float b) {
    unsigned ua = __float_as_uint(a);
    unsigned ub = __float_as_uint(b);
    ua += 0x7fffu + ((ua >> 16) & 1u);
    ub += 0x7fffu + ((ub >> 16) & 1u);
    return (ua >> 16) | (ub & 0xffff0000u);
}

// ---- fp8 e4m3 (OCP) HW cvt ----
__device__ __forceinline__ unsigned fp8x4_from_f32(float v0, float v1, float v2, float v3) {
    int r = 0;
    r = __builtin_amdgcn_cvt_pk_fp8_f32(v0, v1, r, false);
    r = __builtin_amdgcn_cvt_pk_fp8_f32(v2, v3, r, true);
    return (unsigned)r;
}
template <bool HI>
__device__ __forceinline__ floatx2 fp8x2_to_f32(unsigned w) {
    return __builtin_amdgcn_cvt_pk_f32_fp8((int)w, HI);
}

// async global->LDS DMA, 16 B/lane; LDS dest = wave-uniform base + lane*16.
__device__ __forceinline__ void async16(const float* g, float* l) {
    __builtin_amdgcn_global_load_lds(
        (const __attribute__((address_space(1))) unsigned int*)g,
        (__attribute__((address_space(3))) unsigned int*)l, 16, 0, 0);
}

__device__ __forceinline__ int bucket_of(float cx, float cy, int b) {
    int x0 = (int)floorf(cx * (float)(NW - 1));
    int y0 = (int)floorf(cy * (float)(NH - 1));
    x0 = min(max(x0, 0), NW - 1);
    y0 = min(max(y0, 0), NH - 1);
    return b * 256 + (y0 >> 3) * 16 + (x0 >> 3);
}

// prep: blocks [0,16) compute Wf = W1 @ Wp (fp32 VALU, rounded once to bf16);
// block 16 zeros the bucket counters.
__global__ __launch_bounds__(256)
void prep_kernel(const float* __restrict__ W1, const float* __restrict__ Wp,
                 unsigned short* __restrict__ Wfbf, int* __restrict__ counts)
{
    const int bi = blockIdx.x;
    const int t  = threadIdx.x;
    if (bi == 16) {
        counts[t*4+0] = 0; counts[t*4+1] = 0; counts[t*4+2] = 0; counts[t*4+3] = 0;
        return;
    }
    const int e  = bi*8 + (t >> 5);
    const int c0 = (t & 31) * 8;
    float acc[8];
    #pragma unroll
    for (int j = 0; j < 8; ++j) acc[j] = 0.f;
    const float* w1r = W1 + (size_t)e*ND;
    const float* wpc = Wp + c0;
    for (int d = 0; d < ND; ++d) {
        const float s = w1r[d];
        float4 p0 = *(const float4*)(wpc + (size_t)d*NC);
        float4 p1 = *(const float4*)(wpc + (size_t)d*NC + 4);
        acc[0] = fmaf(s, p0.x, acc[0]); acc[1] = fmaf(s, p0.y, acc[1]);
        acc[2] = fmaf(s, p0.z, acc[2]); acc[3] = fmaf(s, p0.w, acc[3]);
        acc[4] = fmaf(s, p1.x, acc[4]); acc[5] = fmaf(s, p1.y, acc[5]);
        acc[6] = fmaf(s, p1.z, acc[6]); acc[7] = fmaf(s, p1.w, acc[7]);
    }
    uint4 pk = make_uint4(pk_bf16(acc[0],acc[1]), pk_bf16(acc[2],acc[3]),
                          pk_bf16(acc[4],acc[5]), pk_bf16(acc[6],acc[7]));
    *(uint4*)&Wfbf[(size_t)e*NC + c0] = pk;
}

// Fused: blocks [0,128) bucket-scatter; [128,1152) projection GEMM
// vmf[b][p][e] = sum_c Wf[e][c]*fmap[b][c][p], fp8 e4m3 channel-last.
// d-HALF per block. fmap chunks (32ch x 128px fp32 = 16 KB) staged via
// DOUBLE-BUFFERED async global_load_lds (width 16): DMA engine holds the
// in-flight loads, so the VALU scheduler cannot re-batch them (rounds 8-10's
// register/sw prefetch were all compiler-defeated at 42us).
// Block map: XCD x = bi&7 owns BOTH d-halves of a tile -> fmap tile's second
// read hits that XCD's L2 (round 10: twins on different XCDs, FETCH 66 MB).
__global__ __launch_bounds__(512, 4)
void proj_fill_kernel(const float* __restrict__ fmap,
                      const unsigned short* __restrict__ Wfbf,
                      const float* __restrict__ coords,
                      unsigned char* __restrict__ vmf,
                      int* __restrict__ counts, int* __restrict__ order)
{
    const int bi0 = blockIdx.x;
    if (bi0 < 128) {         // ---- bucket scatter ----
        const int g = bi0 * 512 + threadIdx.x;
        const float cx = coords[(size_t)g*2 + 0];
        const float cy = coords[(size_t)g*2 + 1];
        const int bkt = bucket_of(cx, cy, g >> 14);
        const int pos = atomicAdd(&counts[bkt], 1);
        if (pos < CAP) order[bkt*CAP + pos] = g;
        return;
    }
    const int bi = bi0 - 128;            // [0, 1024)
    __shared__ float stage[2][32*128];         // 2 x 16 KB fmap chunk buffers
    __shared__ unsigned short awp[4*8*64*8];   // A-fragments, 32 KB

    const int t    = threadIdx.x;
    const int lane = t & 63;
    const int w    = t >> 6;
    const int l15  = lane & 15;
    const int q    = lane >> 4;
    const int cq   = q * 8;

    // twin-XCD mapping: x owns both halves of tile (b, slot)
    const int x    = bi & 7;                       // XCD home
    const int m    = bi >> 3;                      // [0,128)
    const int h    = m & 1;                        // d-half
    const int slot = ((x & 1) << 6) | (m >> 1);    // [0,128)
    const int b    = x >> 1;                       // 2 XCDs per batch
    const int p0   = slot * 128;
    const int p    = p0 + w*16 + l15;

    // ---- stage this half's Wf rows -> LDS A-fragments ----
    {
        const int dt  = w >> 1;
        const int ch0 = (w & 1) * 4;
        #pragma unroll
        for (int cc = 0; cc < 4; ++cc) {
            const int ch = ch0 + cc;
            uint4 v = *(const uint4*)&Wfbf[(size_t)(h*64 + dt*16 + l15)*NC + ch*32 + cq];
            *(uint4*)&awp[((dt*8 + ch)*64 + lane)*8] = v;
        }
    }

    // wave w stages channels w*4 .. w*4+3 of each chunk (2 async issues x 2 ch)
    const float* fb = fmap + (size_t)b*NC*NHW + p0 + (lane & 31)*4;
    const int cw = w*4 + (lane >> 5);

    // prologue: stage chunk 0 into buf 0
    #pragma unroll
    for (int i = 0; i < 2; ++i)
        async16(fb + (size_t)(cw + i*2)*NHW, &stage[0][(w*4 + i*2)*128]);

    __syncthreads();   // drains chunk-0 DMA + A-fragment stores

    floatx4 acc[4];
    #pragma unroll
    for (int i = 0; i < 4; ++i) acc[i] = (floatx4)(0.f);

    #pragma unroll
    for (int c0 = 0; c0 < 8; ++c0) {
        const int s = c0 & 1;
        if (c0 < 7) {   // prefetch next chunk into the other buffer
            #pragma unroll
            for (int i = 0; i < 2; ++i)
                async16(fb + (size_t)((c0+1)*32 + cw + i*2)*NHW,
                        &stage[s^1][(w*4 + i*2)*128]);
        }
        // B fragment from LDS: k = cq+j, px = w*16+l15
        float f[8];
        #pragma unroll
        for (int j = 0; j < 8; ++j)
            f[j] = stage[s][(cq + j)*128 + w*16 + l15];
        union { short8 v; unsigned u[4]; } bc;
        #pragma unroll
        for (int j = 0; j < 4; ++j) bc.u[j] = pk_bf16(f[2*j], f[2*j+1]);
        #pragma unroll
        for (int dt = 0; dt < 4; ++dt) {
            short8 afr = *(const short8*)&awp[((dt*8 + c0)*64 + lane)*8];
            acc[dt] = __builtin_amdgcn_mfma_f32_16x16x32_bf16(afr, bc.v, acc[dt], 0, 0, 0);
        }
        __syncthreads();   // all waves done reading buf s; drains prefetch DMA
    }
    // ---- epilogue: C row=(q*4+reg)->e, col=l15->p; 4 fp8 per dword ----
    unsigned char* vrow = vmf + ((size_t)(b*NHW + p))*ND + h*64;
    #pragma unroll
    for (int dt = 0; dt < 4; ++dt) {
        floatx4 v = acc[dt];
        *(unsigned*)&vrow[dt*16 + q*4] = fp8x4_from_f32(v[0], v[1], v[2], v[3]);
    }
}

// Gather over spatially-bucketed points. vmf holds W1-folded features:
// h = relu(stencil_mean + b1); out = coords + tanh(W2 h + b2)*MD.
// 8 lanes per point (16 fp8 ch each), shfl_xor reduce, NO LDS, NO barriers.
__global__ __launch_bounds__(512, 4)
void gather_kernel(const unsigned char* __restrict__ vmf, const float* __restrict__ coords,
                   const int* __restrict__ counts, const int* __restrict__ order,
                   const float* __restrict__ b1, const float* __restrict__ W2,
                   const float* __restrict__ b2, float* __restrict__ out)
{
    const int t   = threadIdx.x;
    const int bkt = blockIdx.x;
    const int n   = min(counts[bkt], CAP);
    const int grp = t >> 3;
    const int c8  = t & 7;
    const int e0  = c8 * 16;
    const float b20 = b2[0], b21 = b2[1];
    const float MD = 0.5f / 512.0f;
    const float s9 = 1.f / 9.f;

    for (int i = grp; i < n; i += 64) {
        const int g = order[bkt*CAP + i];
        const int b = g >> 14;
        const float cx = coords[(size_t)g*2 + 0];
        const float cy = coords[(size_t)g*2 + 1];
        const float ix = cx * (float)(NW - 1);
        const float iy = cy * (float)(NH - 1);
        const float x0f = floorf(ix), y0f = floorf(iy);
        const int x0 = (int)x0f, y0 = (int)y0f;
        const float wx1 = ix - x0f, wy1 = iy - y0f;
        const float wxv[4] = {1.f - wx1, 1.f, 1.f, wx1};
        const float wyv[4] = {1.f - wy1, 1.f, 1.f, wy1};
        floatx2 acc[8];
        #pragma unroll
        for (int k = 0; k < 8; ++k) acc[k] = (floatx2)(0.f);
        const unsigned char* vmb = vmf + (size_t)b*NHW*ND + e0;
        #pragma unroll
        for (int j = 0; j < 4; ++j) {
            const int Y  = y0 - 1 + j;
            const int Yc = min(max(Y, 0), NH-1);
            const bool vy = (Y >= 0) & (Y < NH);
            #pragma unroll
            for (int ii = 0; ii < 4; ++ii) {
                const int X  = x0 - 1 + ii;
                const int Xc = min(max(X, 0), NW-1);
                const bool vx = (X >= 0) & (X < NW);
                const float wgt = (vx & vy) ? wxv[ii]*wyv[j] : 0.f;  // zeros pad
                uint4 u = *(const uint4*)(vmb + (size_t)(Yc*NW + Xc)*ND);
                const floatx2 w2v = {wgt, wgt};
                acc[0] += w2v * fp8x2_to_f32<false>(u.x);
                acc[1] += w2v * fp8x2_to_f32<true >(u.x);
                acc[2] += w2v * fp8x2_to_f32<false>(u.y);
                acc[3] += w2v * fp8x2_to_f32<true >(u.y);
                acc[4] += w2v * fp8x2_to_f32<false>(u.z);
                acc[5] += w2v * fp8x2_to_f32<true >(u.z);
                acc[6] += w2v * fp8x2_to_f32<false>(u.w);
                acc[7] += w2v * fp8x2_to_f32<true >(u.w);
            }
        }
        // epilogue: bias + relu + W2 dot over this lane's 16 channels
        float s0 = 0.f, s1 = 0.f;
        #pragma unroll
        for (int k = 0; k < 8; ++k) {
            float2 bb = *(const float2*)&b1[e0 + 2*k];
            float h0 = fmaxf(fmaf(acc[k].x, s9, bb.x), 0.f);
            float h1 = fmaxf(fmaf(acc[k].y, s9, bb.y), 0.f);
            float2 wa = *(const float2*)&W2[e0 + 2*k];
            float2 wb = *(const float2*)&W2[ND + e0 + 2*k];
            s0 = fmaf(h0, wa.x, fmaf(h1, wa.y, s0));
            s1 = fmaf(h0, wb.x, fmaf(h1, wb.y, s1));
        }
        s0 += __shfl_xor(s0, 1); s0 += __shfl_xor(s0, 2); s0 += __shfl_xor(s0, 4);
        s1 += __shfl_xor(s1, 1); s1 += __shfl_xor(s1, 2); s1 += __shfl_xor(s1, 4);
        if (c8 == 0) {
            float2 o = make_float2(cx + tanhf(s0 + b20) * MD,
                                   cy + tanhf(s1 + b21) * MD);
            *(float2*)&out[(size_t)g*2] = o;
        }
    }
}

extern "C" void kernel_launch(void* const* d_in, const int* in_sizes, int n_in,
                              void* d_out, int out_size, void* d_ws, size_t ws_size,
                              hipStream_t stream)
{
    const float* fmap   = (const float*)d_in[0];
    const float* coords = (const float*)d_in[1];
    const float* Wp     = (const float*)d_in[2];
    const float* W1     = (const float*)d_in[3];
    const float* b1     = (const float*)d_in[4];
    const float* W2     = (const float*)d_in[5];
    const float* b2     = (const float*)d_in[6];
    float* out = (float*)d_out;

    // ws layout
    unsigned char* vmf = (unsigned char*)d_ws;                        // 8 MB fp8
    char* base = (char*)d_ws + (size_t)NB*NHW*ND;
    unsigned short* Wfbf = (unsigned short*)base;                     // 64 KB bf16
    int* counts = (int*)(base + 65536);                               // 4 KB
    int* order  = (int*)(base + 65536 + 4096);                        // 768 KB

    prep_kernel     <<<dim3(17),         256, 0, stream>>>(W1, Wp, Wfbf, counts);
    proj_fill_kernel<<<dim3(128 + 1024), 512, 0, stream>>>(fmap, Wfbf, coords,
                                                           vmf, counts, order);
    gather_kernel   <<<dim3(NBKT),       512, 0, stream>>>(vmf, coords, counts, order,
                                                           b1, W2, b2, out);
}